// Round 1
// 224.124 us; speedup vs baseline: 1.0131x; 1.0131x over previous
//
#include <hip/hip_runtime.h>

#define C_DIM 256
#define K_DIM 128
#define HW_DIM 64
#define PIX 4096
#define N_IMG 32

using short8 = __attribute__((ext_vector_type(8))) short;
using f32x4  = __attribute__((ext_vector_type(4))) float;

// CK-style barrier: waits own LDS ops (lgkmcnt) only — leaves global-load
// prefetches (vmcnt) in flight across the barrier, unlike __syncthreads().
__device__ __forceinline__ void lds_barrier() {
    asm volatile("s_waitcnt lgkmcnt(0)\n\ts_barrier" ::: "memory");
}

__device__ __forceinline__ unsigned long long umin64(unsigned long long a, unsigned long long b) {
    return a < b ? a : b;
}
__device__ __forceinline__ unsigned mono(float d) {
    unsigned u = __float_as_uint(d);
    return u ^ ((u & 0x80000000u) ? 0xFFFFFFFFu : 0x80000000u);
}

// Truncation split: v = hi + mid + lo, each term = top-16-bit bitmask value
// (exact Sterbenz residuals; lo ~ 2^-16 * v). Cheap: and/sub only.
__device__ __forceinline__ void split3t(float v, unsigned& hu, unsigned& mu, unsigned& lu) {
    unsigned u = __float_as_uint(v);
    unsigned hf = u & 0xffff0000u;
    float r1 = v - __uint_as_float(hf);
    unsigned r1u = __float_as_uint(r1);
    unsigned mf = r1u & 0xffff0000u;
    float r2 = r1 - __uint_as_float(mf);
    hu = u; mu = r1u; lu = __float_as_uint(r2);   // consumers take >>16
}

// P: per cluster k: trunc 3-way split -> Bt[k][768] (planes hi/mid/lo) + exact c2
__global__ __launch_bounds__(64) void prep_kernel(const float* __restrict__ cl,
                                                  unsigned short* __restrict__ Bt,
                                                  float* __restrict__ c2) {
    int k = blockIdx.x;
    int lane = threadIdx.x;
    const float4* row = (const float4*)(cl + k * C_DIM);
    float4 v = row[lane];
    float vv[4] = {v.x, v.y, v.z, v.w};
    unsigned short* bk = Bt + k * 768 + lane * 4;
#pragma unroll
    for (int i = 0; i < 4; ++i) {
        unsigned hu, mu, lu;
        split3t(vv[i], hu, mu, lu);
        bk[i]       = (unsigned short)(hu >> 16);
        bk[256 + i] = (unsigned short)(mu >> 16);
        bk[512 + i] = (unsigned short)(lu >> 16);
    }
    if (lane == 0) {   // identical op order to proven-exact c2
        float s = 0.f;
#pragma unroll
        for (int i = 0; i < C_DIM / 4; ++i) {
            float4 u = row[i];
            s = fmaf(u.x, u.x, s);
            s = fmaf(u.y, u.y, s);
            s = fmaf(u.z, u.z, s);
            s = fmaf(u.w, u.w, s);
        }
        c2[k] = s;
    }
}

// Convert one 32-channel x chunk (xr[16] per thread, this thread's c-half)
// into 3 bf16 planes at Aw (FRAGMENT ORDER layout) + x2 accumulation.
// Op order identical to the proven-exact kernel.
__device__ __forceinline__ void convert_tile(const float xr[16], unsigned short* Aw,
                                             int wbase, float& x2part) {
#pragma unroll
    for (int g = 0; g < 2; ++g) {
        unsigned p0[4], p1[4], p2[4];
#pragma unroll
        for (int jj = 0; jj < 4; ++jj) {
            float v0 = xr[g * 8 + jj * 2], v1 = xr[g * 8 + jj * 2 + 1];
            unsigned h0, m0, l0, h1, m1, l1;
            split3t(v0, h0, m0, l0);
            split3t(v1, h1, m1, l1);
            p0[jj] = (h0 >> 16) | (h1 & 0xffff0000u);
            p1[jj] = (m0 >> 16) | (m1 & 0xffff0000u);
            p2[jj] = (l0 >> 16) | (l1 & 0xffff0000u);
            x2part = fmaf(v0, v0, x2part);
            x2part = fmaf(v1, v1, x2part);
        }
        int base = wbase + g * 128;   // (q = h*2+g) * 16 lanes * 8 ushorts
        *(uint4*)&Aw[base]        = make_uint4(p0[0], p0[1], p0[2], p0[3]);
        *(uint4*)&Aw[4096 + base] = make_uint4(p1[0], p1[1], p1[2], p1[3]);
        *(uint4*)&Aw[8192 + base] = make_uint4(p2[0], p2[1], p2[2], p2[3]);
    }
}

// MFMA quarter-step: 6 cross-term plane pairs, per-acc term order identical
// to proven rounds (pa ascending then pb ascending).
__device__ __forceinline__ void mfma_block(const unsigned short* Ac, const short8 bv[3][2],
                                           f32x4 acc[8][2], int lane) {
#pragma unroll
    for (int pa = 0; pa < 3; ++pa) {
#pragma unroll
        for (int mg = 0; mg < 4; ++mg) {
            const int m0 = mg * 2, m1 = mg * 2 + 1;
            short8 af0 = *(const short8*)&Ac[pa * 4096 + m0 * 512 + lane * 8];
            short8 af1 = *(const short8*)&Ac[pa * 4096 + m1 * 512 + lane * 8];
#pragma unroll
            for (int pb2 = 0; pb2 < 3 - pa; ++pb2) {
                acc[m0][0] = __builtin_amdgcn_mfma_f32_16x16x32_bf16(af0, bv[pb2][0], acc[m0][0], 0, 0, 0);
                acc[m0][1] = __builtin_amdgcn_mfma_f32_16x16x32_bf16(af0, bv[pb2][1], acc[m0][1], 0, 0, 0);
                acc[m1][0] = __builtin_amdgcn_mfma_f32_16x16x32_bf16(af1, bv[pb2][0], acc[m1][0], 0, 0, 0);
                acc[m1][1] = __builtin_amdgcn_mfma_f32_16x16x32_bf16(af1, bv[pb2][1], acc[m1][1], 0, 0, 0);
            }
        }
    }
}

// Main: block = 256 thr (4 waves), S[128px][128k] via 16x16x32 bf16 MFMA.
// ROUND-NEW: LDS double-buffered Ap[2] -> ONE lds_barrier per K-chunk and a
// branch-free iteration body: convert(tile ci+1 -> buf nxt) + xr prefetch +
// MFMA(buf cur) live in one basic block so the scheduler co-issues convert
// VALU with the MFMA pipe (they were phase-serialized before: Mfma=VALU=23%).
// Numerics are bit-identical: same split/term/epilogue op order.
__global__ __launch_bounds__(256) void main_kernel(
    const float* __restrict__ x, const unsigned short* __restrict__ Bt,
    const float* __restrict__ c2v, unsigned char* __restrict__ code) {

    __shared__ __align__(16) unsigned short Ap[2][12288];   // 2 x 24576 B
    __shared__ float x2p[2][128];                           // 1024 B
    unsigned long long* red = (unsigned long long*)Ap;      // aliased (epilogue only)

    const int t    = threadIdx.x;
    const int lane = t & 63;
    const int w    = t >> 6;
    const int q    = lane >> 4;
    const int l15  = lane & 15;

    const int px = t & 127;        // conversion: this thread's pixel row
    const int h  = t >> 7;         // conversion: c-half (0: c 0-15, 1: c 16-31)

    const int b   = blockIdx.x;
    const int img = b >> 5;
    const int pb  = (b & 31) * 128;

    // Uniform base pointer; per-lane part stays a 32-bit index (SGPR base +
    // voffset addressing, less per-load VALU).
    const float* xb = x + (size_t)img * (C_DIM * PIX) + pb;

    f32x4 acc[8][2];
#pragma unroll
    for (int m = 0; m < 8; ++m)
#pragma unroll
        for (int ns = 0; ns < 2; ++ns) acc[m][ns] = (f32x4){0.f, 0.f, 0.f, 0.f};

    float xr[16];
#pragma unroll
    for (int j = 0; j < 16; ++j) xr[j] = xb[(h * 16 + j) * PIX + px];

    float x2part = 0.f;
    const unsigned short* btb = Bt + (w * 32 + l15) * 768 + q * 8;

    // convert-phase LDS write base (ushort idx within a plane)
    const int wbase = (px >> 4) * 512 + (px & 15) * 8 + h * 2 * 128;

    // ---- prologue: tile 0 -> buf0, prefetch tile 1 ----
    convert_tile(xr, Ap[0], wbase, x2part);
#pragma unroll
    for (int j = 0; j < 16; ++j) xr[j] = xb[(32 + h * 16 + j) * PIX + px];
    lds_barrier();

#pragma unroll 1
    for (int ci = 0; ci < 7; ++ci) {
        // B-fragments for this chunk (L2-hot); consumed after the convert
        // (~300+ cyc of cover).
        short8 bv[3][2];
#pragma unroll
        for (int p = 0; p < 3; ++p) {
            bv[p][0] = *(const short8*)(btb + p * 256 + ci * 32);
            bv[p][1] = *(const short8*)(btb + 16 * 768 + p * 256 + ci * 32);
        }

        // convert tile ci+1 into the buffer MFMA is NOT reading this iter
        convert_tile(xr, Ap[(ci + 1) & 1], wbase, x2part);
        x2p[h][px] = x2part;   // unconditional (branch-free); final write ci==6

        // prefetch tile ci+2 (wraps to an L2-hot tile at ci==6; value unused)
        const int tnext = (ci + 2) & 7;
#pragma unroll
        for (int j = 0; j < 16; ++j)
            xr[j] = xb[(tnext * 32 + h * 16 + j) * PIX + px];

        // MFMA on current buffer — same BB as the convert above, so the
        // scheduler interleaves convert VALU with MFMA/ds_read stalls.
        mfma_block(Ap[ci & 1], bv, acc, lane);

        // one barrier per chunk: lgkmcnt(0) drains this wave's Ap reads AND
        // its buf-nxt writes; after s_barrier the read buffer is safely
        // recyclable and the written buffer is visible.
        lds_barrier();
    }

    // ---- tail chunk (ci = 7): MFMA only, no convert/prefetch ----
    {
        short8 bv[3][2];
#pragma unroll
        for (int p = 0; p < 3; ++p) {
            bv[p][0] = *(const short8*)(btb + p * 256 + 7 * 32);
            bv[p][1] = *(const short8*)(btb + 16 * 768 + p * 256 + 7 * 32);
        }
        mfma_block(Ap[1], bv, acc, lane);
        lds_barrier();
    }

    // ---- epilogue: dist = (x2 - 2*S) + c2, argmin (proven exact) ----
    const float c2a0 = c2v[w * 32 + l15];
    const float c2a1 = c2v[w * 32 + 16 + l15];
    const unsigned n0 = (unsigned)(w * 32 + l15);
    const unsigned n1 = n0 + 16;

#pragma unroll
    for (int m = 0; m < 8; ++m) {
#pragma unroll
        for (int r = 0; r < 4; ++r) {
            int pxl = m * 16 + q * 4 + r;             // C/D: row = quad*4 + reg
            float x2v = x2p[0][pxl] + x2p[1][pxl];
            float d0 = (x2v - 2.0f * acc[m][0][r]) + c2a0;
            float d1 = (x2v - 2.0f * acc[m][1][r]) + c2a1;
            unsigned long long k0 = ((unsigned long long)mono(d0) << 32) | n0;
            unsigned long long k1 = ((unsigned long long)mono(d1) << 32) | n1;
            unsigned long long best = umin64(k0, k1);
            best = umin64(best, __shfl_xor(best, 1));
            best = umin64(best, __shfl_xor(best, 2));
            best = umin64(best, __shfl_xor(best, 4));
            best = umin64(best, __shfl_xor(best, 8));
            if (l15 == 0) red[w * 128 + pxl] = best;
        }
    }
    lds_barrier();

    if (t < 128) {
        unsigned long long m0 = umin64(umin64(red[t], red[128 + t]),
                                       umin64(red[256 + t], red[384 + t]));
        code[(size_t)img * PIX + pb + t] = (unsigned char)(m0 & 0xFFu);
    }
}

// K2: 4 histogram tiles per 256-thread block (proven-exact kernel)
__global__ __launch_bounds__(256) void hist_kernel(const unsigned char* __restrict__ code,
                                                   float* __restrict__ out) {
    __shared__ int hist[4][K_DIM + 1];
    int wid = threadIdx.x >> 6, lane = threadIdx.x & 63;
    int b = blockIdx.x * 4 + wid;
    int n = b >> 6, sy = (b >> 3) & 7, sx = b & 7;

    hist[wid][lane] = 0;
    hist[wid][lane + 64] = 0;
    if (lane == 0) hist[wid][128] = 0;
    __syncthreads();

    int hh = sy * 8 + (lane >> 3);
    int ww = sx * 8 + (lane & 7);
    int c = code[n * PIX + hh * HW_DIM + ww];
    atomicAdd(&hist[wid][c + 1], 1);
    __syncthreads();

    const float inv = 1.0f / 64.0f;
    out[(size_t)b * (K_DIM + 1) + lane] = hist[wid][lane] * inv;
    out[(size_t)b * (K_DIM + 1) + 64 + lane] = hist[wid][lane + 64] * inv;
    if (lane == 0) out[(size_t)b * (K_DIM + 1) + 128] = hist[wid][128] * inv;
}

extern "C" void kernel_launch(void* const* d_in, const int* in_sizes, int n_in,
                              void* d_out, int out_size, void* d_ws, size_t ws_size,
                              hipStream_t stream) {
    const float* x  = (const float*)d_in[0];       // (32, 256, 64, 64) fp32
    const float* cl = (const float*)d_in[1];       // (128, 256) fp32
    float* out = (float*)d_out;                    // (32, 64, 129) fp32

    unsigned short* Bt = (unsigned short*)d_ws;                  // 196608 B
    float* c2 = (float*)((char*)d_ws + 196608);                  // 512 B
    unsigned char* code = (unsigned char*)d_ws + 197120;         // 131072 B

    prep_kernel<<<K_DIM, 64, 0, stream>>>(cl, Bt, c2);
    main_kernel<<<(N_IMG * PIX) / 128, 256, 0, stream>>>(x, Bt, c2, code);
    hist_kernel<<<(N_IMG * 64) / 4, 256, 0, stream>>>(code, out);
}

// Round 2
// 217.021 us; speedup vs baseline: 1.0463x; 1.0327x over previous
//
#include <hip/hip_runtime.h>

#define C_DIM 256
#define K_DIM 128
#define HW_DIM 64
#define PIX 4096
#define N_IMG 32

using short8 = __attribute__((ext_vector_type(8))) short;
using f32x4  = __attribute__((ext_vector_type(4))) float;

// CK-style barrier: waits own LDS ops (lgkmcnt) only — leaves global-load
// prefetches (vmcnt) in flight across the barrier, unlike __syncthreads().
__device__ __forceinline__ void lds_barrier() {
    asm volatile("s_waitcnt lgkmcnt(0)\n\ts_barrier" ::: "memory");
}

__device__ __forceinline__ unsigned long long umin64(unsigned long long a, unsigned long long b) {
    return a < b ? a : b;
}
__device__ __forceinline__ unsigned mono(float d) {
    unsigned u = __float_as_uint(d);
    return u ^ ((u & 0x80000000u) ? 0xFFFFFFFFu : 0x80000000u);
}

// Truncation split: v = hi + mid + lo, each term = top-16-bit bitmask value
// (exact Sterbenz residuals; lo ~ 2^-16 * v). Cheap: and/sub only.
__device__ __forceinline__ void split3t(float v, unsigned& hu, unsigned& mu, unsigned& lu) {
    unsigned u = __float_as_uint(v);
    unsigned hf = u & 0xffff0000u;
    float r1 = v - __uint_as_float(hf);
    unsigned r1u = __float_as_uint(r1);
    unsigned mf = r1u & 0xffff0000u;
    float r2 = r1 - __uint_as_float(mf);
    hu = u; mu = r1u; lu = __float_as_uint(r2);   // consumers take >>16
}

// P: per cluster k: trunc 3-way split -> Bt[k][768] (planes hi/mid/lo) + exact c2
__global__ __launch_bounds__(64) void prep_kernel(const float* __restrict__ cl,
                                                  unsigned short* __restrict__ Bt,
                                                  float* __restrict__ c2) {
    int k = blockIdx.x;
    int lane = threadIdx.x;
    const float4* row = (const float4*)(cl + k * C_DIM);
    float4 v = row[lane];
    float vv[4] = {v.x, v.y, v.z, v.w};
    unsigned short* bk = Bt + k * 768 + lane * 4;
#pragma unroll
    for (int i = 0; i < 4; ++i) {
        unsigned hu, mu, lu;
        split3t(vv[i], hu, mu, lu);
        bk[i]       = (unsigned short)(hu >> 16);
        bk[256 + i] = (unsigned short)(mu >> 16);
        bk[512 + i] = (unsigned short)(lu >> 16);
    }
    if (lane == 0) {   // identical op order to proven-exact c2
        float s = 0.f;
#pragma unroll
        for (int i = 0; i < C_DIM / 4; ++i) {
            float4 u = row[i];
            s = fmaf(u.x, u.x, s);
            s = fmaf(u.y, u.y, s);
            s = fmaf(u.z, u.z, s);
            s = fmaf(u.w, u.w, s);
        }
        c2[k] = s;
    }
}

// Main: block = 256 thr (4 waves), S[128px][128k] via 16x16x32 bf16 MFMA,
// 6 cross-term pairs (h,h)(h,m)(h,l)(m,h)(m,m)(l,h); per-acc term order
// identical to proven rounds. A staged in LDS in FRAGMENT ORDER.
// ROUND-NEW vs proven 88us kernel (two changes, numerics bit-identical):
//  1. __launch_bounds__(256,4): cap unified VGPR at 128 -> 4 blocks/CU.
//     Grid is exactly 1024 = 256 CU x 4 blocks -> all blocks co-resident,
//     eliminating the 256-block tail that ran at 1 block/CU (the measured
//     23% time-avg occupancy = (12w+4w)/2 tail math).
//  2. bv loads moved AFTER convert (before xr prefetch): shrinks bv's
//     24-reg live range so the 128-reg cap fits without spills, while
//     keeping bv issued BEFORE the 16 xr loads (first MFMA waits
//     vmcnt(16), xr prefetch stays in flight across the barrier).
__global__ __launch_bounds__(256, 4) void main_kernel(
    const float* __restrict__ x, const unsigned short* __restrict__ Bt,
    const float* __restrict__ c2v, unsigned char* __restrict__ code) {

    __shared__ __align__(16) unsigned short Ap[3 * 4096];   // 24576 B
    __shared__ float x2p[2][128];                           // 1024 B
    unsigned long long* red = (unsigned long long*)Ap;      // aliased (epilogue only)

    const int t    = threadIdx.x;
    const int lane = t & 63;
    const int w    = t >> 6;
    const int q    = lane >> 4;
    const int l15  = lane & 15;

    const int px = t & 127;        // conversion: this thread's pixel row
    const int h  = t >> 7;         // conversion: c-half (0: c 0-15, 1: c 16-31)

    const int b   = blockIdx.x;
    const int img = b >> 5;
    const int pb  = (b & 31) * 128;

    const float* xg = x + (size_t)img * (C_DIM * PIX) + pb + px;

    f32x4 acc[8][2];
#pragma unroll
    for (int m = 0; m < 8; ++m)
#pragma unroll
        for (int ns = 0; ns < 2; ++ns) acc[m][ns] = (f32x4){0.f, 0.f, 0.f, 0.f};

    float xr[16];
#pragma unroll
    for (int j = 0; j < 16; ++j) xr[j] = xg[(size_t)(h * 16 + j) * PIX];

    float x2part = 0.f;
    const unsigned short* btb = Bt + (w * 32 + l15) * 768 + q * 8;

    // convert-phase LDS write base (ushort idx within a plane)
    const int wbase = (px >> 4) * 512 + (px & 15) * 8 + h * 2 * 128;

#pragma unroll 1
    for (int ci = 0; ci < 8; ++ci) {
        // ---- convert xr -> 3 bf16 planes in LDS (trunc split) + x2 ----
#pragma unroll
        for (int g = 0; g < 2; ++g) {
            unsigned p0[4], p1[4], p2[4];
#pragma unroll
            for (int jj = 0; jj < 4; ++jj) {
                float v0 = xr[g * 8 + jj * 2], v1 = xr[g * 8 + jj * 2 + 1];
                unsigned h0, m0, l0, h1, m1, l1;
                split3t(v0, h0, m0, l0);
                split3t(v1, h1, m1, l1);
                p0[jj] = (h0 >> 16) | (h1 & 0xffff0000u);
                p1[jj] = (m0 >> 16) | (m1 & 0xffff0000u);
                p2[jj] = (l0 >> 16) | (l1 & 0xffff0000u);
                x2part = fmaf(v0, v0, x2part);
                x2part = fmaf(v1, v1, x2part);
            }
            int base = wbase + g * 128;   // (q = h*2+g) * 16 lanes * 8 ushorts
            *(uint4*)&Ap[base]            = make_uint4(p0[0], p0[1], p0[2], p0[3]);
            *(uint4*)&Ap[4096 + base]     = make_uint4(p1[0], p1[1], p1[2], p1[3]);
            *(uint4*)&Ap[8192 + base]     = make_uint4(p2[0], p2[1], p2[2], p2[3]);
        }
        if (ci == 7) x2p[h][px] = x2part;

        // ---- B-fragments: 6 unique (plane x n-half), L2-hot. Issued AFTER
        // convert (short live range, fits the 128-reg cap) but BEFORE the xr
        // prefetch (vmcnt FIFO: first MFMA waits vmcnt(16), xr stays in
        // flight). Consumed after the barrier ~200+ cyc later.
        short8 bv[3][2];
#pragma unroll
        for (int p = 0; p < 3; ++p) {
            bv[p][0] = *(const short8*)(btb + p * 256 + ci * 32);
            bv[p][1] = *(const short8*)(btb + 16 * 768 + p * 256 + ci * 32);
        }

        // ---- prefetch next x chunk (vmcnt survives the barriers below) ----
        if (ci < 7) {
#pragma unroll
            for (int j = 0; j < 16; ++j)
                xr[j] = xg[(size_t)((ci + 1) * 32 + h * 16 + j) * PIX];
        }

        lds_barrier();   // Ap ready (LDS-only wait)

        // ---- MFMA: pa outer, m-pairs, pb inner; per-acc term order =
        // pa ascending then pb ascending (identical to proven rounds).
#pragma unroll
        for (int pa = 0; pa < 3; ++pa) {
#pragma unroll
            for (int mg = 0; mg < 4; ++mg) {
                const int m0 = mg * 2, m1 = mg * 2 + 1;
                short8 af0 = *(const short8*)&Ap[pa * 4096 + m0 * 512 + lane * 8];
                short8 af1 = *(const short8*)&Ap[pa * 4096 + m1 * 512 + lane * 8];
#pragma unroll
                for (int pb2 = 0; pb2 < 3; ++pb2) {
                    if (pb2 < 3 - pa) {
                        acc[m0][0] = __builtin_amdgcn_mfma_f32_16x16x32_bf16(af0, bv[pb2][0], acc[m0][0], 0, 0, 0);
                        acc[m0][1] = __builtin_amdgcn_mfma_f32_16x16x32_bf16(af0, bv[pb2][1], acc[m0][1], 0, 0, 0);
                        acc[m1][0] = __builtin_amdgcn_mfma_f32_16x16x32_bf16(af1, bv[pb2][0], acc[m1][0], 0, 0, 0);
                        acc[m1][1] = __builtin_amdgcn_mfma_f32_16x16x32_bf16(af1, bv[pb2][1], acc[m1][1], 0, 0, 0);
                    }
                }
            }
        }
        lds_barrier();   // all Ap reads done before next convert overwrites
    }

    // ---- epilogue: dist = (x2 - 2*S) + c2, argmin (proven exact) ----
    const float c2a0 = c2v[w * 32 + l15];
    const float c2a1 = c2v[w * 32 + 16 + l15];
    const unsigned n0 = (unsigned)(w * 32 + l15);
    const unsigned n1 = n0 + 16;

#pragma unroll
    for (int m = 0; m < 8; ++m) {
#pragma unroll
        for (int r = 0; r < 4; ++r) {
            int pxl = m * 16 + q * 4 + r;             // C/D: row = quad*4 + reg
            float x2v = x2p[0][pxl] + x2p[1][pxl];
            float d0 = (x2v - 2.0f * acc[m][0][r]) + c2a0;
            float d1 = (x2v - 2.0f * acc[m][1][r]) + c2a1;
            unsigned long long k0 = ((unsigned long long)mono(d0) << 32) | n0;
            unsigned long long k1 = ((unsigned long long)mono(d1) << 32) | n1;
            unsigned long long best = umin64(k0, k1);
            best = umin64(best, __shfl_xor(best, 1));
            best = umin64(best, __shfl_xor(best, 2));
            best = umin64(best, __shfl_xor(best, 4));
            best = umin64(best, __shfl_xor(best, 8));
            if (l15 == 0) red[w * 128 + pxl] = best;
        }
    }
    lds_barrier();

    if (t < 128) {
        unsigned long long m0 = umin64(umin64(red[t], red[128 + t]),
                                       umin64(red[256 + t], red[384 + t]));
        code[(size_t)img * PIX + pb + t] = (unsigned char)(m0 & 0xFFu);
    }
}

// K2: 4 histogram tiles per 256-thread block (proven-exact kernel)
__global__ __launch_bounds__(256) void hist_kernel(const unsigned char* __restrict__ code,
                                                   float* __restrict__ out) {
    __shared__ int hist[4][K_DIM + 1];
    int wid = threadIdx.x >> 6, lane = threadIdx.x & 63;
    int b = blockIdx.x * 4 + wid;
    int n = b >> 6, sy = (b >> 3) & 7, sx = b & 7;

    hist[wid][lane] = 0;
    hist[wid][lane + 64] = 0;
    if (lane == 0) hist[wid][128] = 0;
    __syncthreads();

    int hh = sy * 8 + (lane >> 3);
    int ww = sx * 8 + (lane & 7);
    int c = code[n * PIX + hh * HW_DIM + ww];
    atomicAdd(&hist[wid][c + 1], 1);
    __syncthreads();

    const float inv = 1.0f / 64.0f;
    out[(size_t)b * (K_DIM + 1) + lane] = hist[wid][lane] * inv;
    out[(size_t)b * (K_DIM + 1) + 64 + lane] = hist[wid][lane + 64] * inv;
    if (lane == 0) out[(size_t)b * (K_DIM + 1) + 128] = hist[wid][128] * inv;
}

extern "C" void kernel_launch(void* const* d_in, const int* in_sizes, int n_in,
                              void* d_out, int out_size, void* d_ws, size_t ws_size,
                              hipStream_t stream) {
    const float* x  = (const float*)d_in[0];       // (32, 256, 64, 64) fp32
    const float* cl = (const float*)d_in[1];       // (128, 256) fp32
    float* out = (float*)d_out;                    // (32, 64, 129) fp32

    unsigned short* Bt = (unsigned short*)d_ws;                  // 196608 B
    float* c2 = (float*)((char*)d_ws + 196608);                  // 512 B
    unsigned char* code = (unsigned char*)d_ws + 197120;         // 131072 B

    prep_kernel<<<K_DIM, 64, 0, stream>>>(cl, Bt, c2);
    main_kernel<<<(N_IMG * PIX) / 128, 256, 0, stream>>>(x, Bt, c2, code);
    hist_kernel<<<(N_IMG * 64) / 4, 256, 0, stream>>>(code, out);
}